// Round 5
// baseline (13.572 us; speedup 1.0000x reference)
//
#include <hip/hip_runtime.h>

namespace {
constexpr int NNODES = 128;
constexpr int NEDGES = 1024;
constexpr int CAP    = 96;     // max incident edges per node per direction
constexpr int NIT    = 12;     // static batched scan: NIT*4 waves = 48 slots
constexpr float PI_F = 3.14159265358979323846f;
}

// ---------------------------------------------------------------------------
// One block per node, one dispatch total.
//  phase 1: scan own Ri/Ro rows (coalesced) -> incident edge lists
//  phase 2: batched predicated column scans (all loads in flight at once)
//           -> sender o(e) / receiver r(e) + column value (one-hot columns)
//  phase 3: wave 0: butterfly-reduce angles mi[0..4], mo[0..2] in-register,
//                   then simulate sub-circuit A (qubits 0..7, 256 amps).
//           wave 1: butterfly-reduce mo[3..4], read X[n,:] directly,
//                   then simulate sub-circuit B (qubits 8,9,10,11,13,14).
//           Qubit 12 is unentangled & unmeasured -> dropped.
// A bit map: reg bit0=q0, reg bit1=q1, lane bit (q-2) = qubit q (q=2..7).
// B bit map: lane bits {0..5} = qubits {8,9,10,11,13,14}.
// ---------------------------------------------------------------------------
__global__ __launch_bounds__(256)
void nodenet_fused(const float* __restrict__ X,
                   const float* __restrict__ ew,
                   const float* __restrict__ Ri,
                   const float* __restrict__ Ro,
                   const float* __restrict__ theta,
                   float* __restrict__ out)
{
    __shared__ int   cin, cout;
    __shared__ int   inE[CAP];  __shared__ float inW[CAP];
    __shared__ int   inO[CAP];  __shared__ float inV[CAP];
    __shared__ int   outE[CAP]; __shared__ float outW[CAP];
    __shared__ int   outR[CAP]; __shared__ float outV[CAP];

    const int n = blockIdx.x, tid = threadIdx.x;
    const int lane = tid & 63, wid = tid >> 6;

    if (tid == 0) { cin = 0; cout = 0; }
    __syncthreads();

    // ---- phase 1: own-row scan, coalesced; append incident edges ----
    #pragma unroll
    for (int j = 0; j < 4; ++j) {
        const int e = tid + j * 256;
        const float riv = Ri[n * NEDGES + e];
        const float rov = Ro[n * NEDGES + e];
        if (riv != 0.f) {
            const int idx = atomicAdd(&cin, 1);
            if (idx < CAP) { inE[idx] = e; inW[idx] = riv * ew[e]; }
        }
        if (rov != 0.f) {
            const int idx = atomicAdd(&cout, 1);
            if (idx < CAP) { outE[idx] = e; outW[idx] = rov * ew[e]; }
        }
    }
    __syncthreads();

    const int ci = min(cin, CAP), co = min(cout, CAP);
    const int total = ci + co;

    // ---- phase 2: batched column scans (one wave per slot, 48 slots) ----
    float va[NIT], vb[NIT];
    #pragma unroll
    for (int it = 0; it < NIT; ++it) {
        const int t = wid + it * 4;
        int e = 0;
        const float* col = Ri;             // dummy default (valid memory)
        if (t < ci)         { e = inE[t];       col = Ro; }
        else if (t < total) { e = outE[t - ci]; col = Ri; }
        va[it] = col[lane * NEDGES + e];
        vb[it] = col[(lane + 64) * NEDGES + e];
    }
    #pragma unroll
    for (int it = 0; it < NIT; ++it) {
        const int t = wid + it * 4;
        if (t < ci) {
            if (va[it] != 0.f) { inO[t] = lane;      inV[t] = va[it]; }
            if (vb[it] != 0.f) { inO[t] = lane + 64; inV[t] = vb[it]; }
        } else if (t < total) {
            const int s = t - ci;
            if (va[it] != 0.f) { outR[s] = lane;      outV[s] = va[it]; }
            if (vb[it] != 0.f) { outR[s] = lane + 64; outV[s] = vb[it]; }
        }
    }
    // fallback for total > 48 (statistically unreachable, kept for safety)
    for (int t = wid + NIT * 4; t < total; t += 4) {
        const bool isIn = t < ci;
        const int e = isIn ? inE[t] : outE[t - ci];
        const float* col = isIn ? Ro : Ri;
        const float v0f = col[lane * NEDGES + e];
        const float v1f = col[(lane + 64) * NEDGES + e];
        if (isIn) {
            if (v0f != 0.f) { inO[t] = lane;      inV[t] = v0f; }
            if (v1f != 0.f) { inO[t] = lane + 64; inV[t] = v1f; }
        } else {
            const int s = t - ci;
            if (v0f != 0.f) { outR[s] = lane;      outV[s] = v0f; }
            if (v1f != 0.f) { outR[s] = lane + 64; outV[s] = v1f; }
        }
    }
    __syncthreads();
    if (wid >= 2) return;

    float c_, s_, t_, v0, v1, v2, v3;
#define CS(i)        __sincosf(0.5f * theta[i], &s_, &c_)

    if (wid == 0) {
        // ---- angles mi[0..4] (v[0..4]) and mo[0..2] (v[5..7]) in-register ----
        float v[8] = {0.f,0.f,0.f,0.f,0.f,0.f,0.f,0.f};
        if (lane < ci) {
            const float wv = inW[lane] * inV[lane];
            const int o = inO[lane] * 5;
            #pragma unroll
            for (int k = 0; k < 5; ++k) v[k] = wv * X[o + k];
        }
        if (lane + 64 < ci) {
            const float wv = inW[lane + 64] * inV[lane + 64];
            const int o = inO[lane + 64] * 5;
            #pragma unroll
            for (int k = 0; k < 5; ++k) v[k] += wv * X[o + k];
        }
        if (lane < co) {
            const float wv = outW[lane] * outV[lane];
            const int r = outR[lane] * 5;
            #pragma unroll
            for (int k = 0; k < 3; ++k) v[5 + k] = wv * X[r + k];
        }
        if (lane + 64 < co) {
            const float wv = outW[lane + 64] * outV[lane + 64];
            const int r = outR[lane + 64] * 5;
            #pragma unroll
            for (int k = 0; k < 3; ++k) v[5 + k] += wv * X[r + k];
        }
        #pragma unroll
        for (int m = 1; m < 64; m <<= 1) {
            #pragma unroll
            for (int k = 0; k < 8; ++k) v[k] += __shfl_xor(v[k], m, 64);
        }

        // ================= circuit A (qubits 0..7) =================
        float ic[8], is[8];
        #pragma unroll
        for (int q = 0; q < 8; ++q) __sincosf(0.5f * v[q], &is[q], &ic[q]);

        float lp = 1.f;
        #pragma unroll
        for (int q = 2; q < 8; ++q) lp *= ((lane >> (q - 2)) & 1) ? is[q] : ic[q];
        float r0 = lp * ic[0] * ic[1];
        float r1 = lp * is[0] * ic[1];
        float r2 = lp * ic[0] * is[1];
        float r3 = lp * is[0] * is[1];

#define RY_REG0      { t_ = r0; r0 = c_*t_ - s_*r1; r1 = fmaf(s_, t_, c_*r1); \
                       t_ = r2; r2 = c_*t_ - s_*r3; r3 = fmaf(s_, t_, c_*r3); }
#define RY_REG1      { t_ = r0; r0 = c_*t_ - s_*r2; r2 = fmaf(s_, t_, c_*r2); \
                       t_ = r1; r1 = c_*t_ - s_*r3; r3 = fmaf(s_, t_, c_*r3); }
#define RY_LANE_A(sh){ const float sg = ((lane >> (sh)) & 1) ? s_ : -s_;      \
                       v0 = __shfl_xor(r0, 1 << (sh), 64);                    \
                       v1 = __shfl_xor(r1, 1 << (sh), 64);                    \
                       v2 = __shfl_xor(r2, 1 << (sh), 64);                    \
                       v3 = __shfl_xor(r3, 1 << (sh), 64);                    \
                       r0 = fmaf(c_, r0, sg*v0); r1 = fmaf(c_, r1, sg*v1);    \
                       r2 = fmaf(c_, r2, sg*v2); r3 = fmaf(c_, r3, sg*v3); }
#define CX_LL_A(csh, tsh) { const bool p = (lane >> (csh)) & 1;               \
                       v0 = __shfl_xor(r0, 1 << (tsh), 64);                   \
                       v1 = __shfl_xor(r1, 1 << (tsh), 64);                   \
                       v2 = __shfl_xor(r2, 1 << (tsh), 64);                   \
                       v3 = __shfl_xor(r3, 1 << (tsh), 64);                   \
                       if (p) { r0 = v0; r1 = v1; r2 = v2; r3 = v3; } }

        CS(0);  RY_REG0;                     // R t0 q0
        CS(1);  RY_REG1;                     // R t1 q1
        t_ = r1; r1 = r3; r3 = t_;           // C(0->1): ctrl reg0, tgt reg1
        CS(2);  RY_LANE_A(0);                // R t2 q2
        CS(3);  RY_LANE_A(1);                // R t3 q3
        CX_LL_A(1, 0);                       // C(3->2)
        CS(4);  RY_LANE_A(2);                // R t4 q4
        CS(5);  RY_LANE_A(3);                // R t5 q5
        CX_LL_A(2, 3);                       // C(4->5)
        CS(6);  RY_LANE_A(4);                // R t6 q6
        CS(7);  RY_LANE_A(5);                // R t7 q7
        CX_LL_A(5, 4);                       // C(7->6)
        CS(15); RY_REG1;                     // R t15 q1
        CS(16); RY_LANE_A(0);                // R t16 q2
        r2 = __shfl_xor(r2, 1, 64);          // C(1->2): ctrl reg1, tgt lane0
        r3 = __shfl_xor(r3, 1, 64);
        CS(14); RY_LANE_A(3);                // R t14 q5
        CS(15); RY_LANE_A(4);                // R t15 q6
        CX_LL_A(4, 3);                       // C(6->5)
        CS(19); RY_LANE_A(0);                // R t19 q2
        CS(20); RY_LANE_A(3);                // R t20 q5
        CX_LL_A(0, 3);                       // C(2->5)
        CS(23); RY_LANE_A(3);                // R t23 q5
        CS(25); RY_REG0;                     // R t25 q0
        CS(26); RY_LANE_A(3);                // R t26 q5
        r1 = __shfl_xor(r1, 8, 64);          // C(0->5): ctrl reg0, tgt lane3
        r3 = __shfl_xor(r3, 8, 64);
        CS(29); RY_LANE_A(3);                // R t29 q5

        float zA = (r0*r0 + r1*r1 + r2*r2 + r3*r3) * (((lane >> 3) & 1) ? -1.f : 1.f);
        #pragma unroll
        for (int m = 1; m < 64; m <<= 1) zA += __shfl_xor(zA, m, 64);
        if (lane == 0) out[n * 2 + 0] = PI_F * (1.f - zA);
    } else {
        // ---- angles mo[3] (va0), mo[4] (va1) in-register ----
        float va0 = 0.f, va1 = 0.f;
        if (lane < co) {
            const float wv = outW[lane] * outV[lane];
            const int r = outR[lane] * 5;
            va0 = wv * X[r + 3];
            va1 = wv * X[r + 4];
        }
        if (lane + 64 < co) {
            const float wv = outW[lane + 64] * outV[lane + 64];
            const int r = outR[lane + 64] * 5;
            va0 += wv * X[r + 3];
            va1 += wv * X[r + 4];
        }
        #pragma unroll
        for (int m = 1; m < 64; m <<= 1) {
            va0 += __shfl_xor(va0, m, 64);
            va1 += __shfl_xor(va1, m, 64);
        }

        // ================= circuit B (qubits 8,9,10,11,13,14) =================
        float c8, s8, c9, s9, c10, s10, c11, s11, c13, s13, c14, s14;
        __sincosf(0.5f * va0,          &s8,  &c8);   // q8  = mo[3]
        __sincosf(0.5f * va1,          &s9,  &c9);   // q9  = mo[4]
        __sincosf(0.5f * X[n*5 + 0],   &s10, &c10);  // q10 = X[n,0]
        __sincosf(0.5f * X[n*5 + 1],   &s11, &c11);  // q11 = X[n,1]
        __sincosf(0.5f * X[n*5 + 3],   &s13, &c13);  // q13 = X[n,3]
        __sincosf(0.5f * X[n*5 + 4],   &s14, &c14);  // q14 = X[n,4]

        float b = ((lane >> 0) & 1) ? s8  : c8;
        b      *= ((lane >> 1) & 1) ? s9  : c9;
        b      *= ((lane >> 2) & 1) ? s10 : c10;
        b      *= ((lane >> 3) & 1) ? s11 : c11;
        b      *= ((lane >> 4) & 1) ? s13 : c13;
        b      *= ((lane >> 5) & 1) ? s14 : c14;

#define RY_B(sh)     { const float sg = ((lane >> (sh)) & 1) ? s_ : -s_;      \
                       v0 = __shfl_xor(b, 1 << (sh), 64);                     \
                       b = fmaf(c_, b, sg*v0); }
#define CX_B(csh, tsh) { v0 = __shfl_xor(b, 1 << (tsh), 64);                  \
                       if ((lane >> (csh)) & 1) b = v0; }

        CS(8);  RY_B(0);                     // R t8  q8
        CS(9);  RY_B(1);                     // R t9  q9
        CX_B(0, 1);                          // C(8->9)
        CS(10); RY_B(2);                     // R t10 q10
        CS(11); RY_B(3);                     // R t11 q11
        CX_B(3, 2);                          // C(11->10)
        CS(13); RY_B(4);                     // R t13 q13
        CX_B(0, 1);                          // C(8->9)
        CS(14); RY_B(5);                     // R t14 q14
        CS(16); RY_B(1);                     // R t16 q9
        CS(17); RY_B(2);                     // R t17 q10
        CX_B(1, 2);                          // C(9->10)
        CS(18); RY_B(4);                     // R t18 q13
        CS(19); RY_B(5);                     // R t19 q14
        CX_B(1, 2);                          // C(9->10)
        CS(21); RY_B(2);                     // R t21 q10
        CS(22); RY_B(4);                     // R t22 q13
        CX_B(4, 2);                          // C(13->10)
        CS(24); RY_B(2);                     // R t24 q10
        CS(27); RY_B(2);                     // R t27 q10
        CS(28); RY_B(5);                     // R t28 q14
        CX_B(5, 2);                          // C(14->10)
        CS(30); RY_B(2);                     // R t30 q10

        float zB = (b * b) * (((lane >> 2) & 1) ? -1.f : 1.f);
        #pragma unroll
        for (int m = 1; m < 64; m <<= 1) zB += __shfl_xor(zB, m, 64);
        if (lane == 0) out[n * 2 + 1] = PI_F * (1.f - zB);
    }
#undef CS
#undef RY_REG0
#undef RY_REG1
#undef RY_LANE_A
#undef CX_LL_A
#undef RY_B
#undef CX_B
}

extern "C" void kernel_launch(void* const* d_in, const int* in_sizes, int n_in,
                              void* d_out, int out_size, void* d_ws, size_t ws_size,
                              hipStream_t stream) {
    (void)in_sizes; (void)n_in; (void)d_ws; (void)ws_size; (void)out_size;
    const float* X     = (const float*)d_in[0];
    const float* ew    = (const float*)d_in[1];
    const float* Ri    = (const float*)d_in[2];
    const float* Ro    = (const float*)d_in[3];
    const float* theta = (const float*)d_in[4];
    float* out = (float*)d_out;

    nodenet_fused<<<NNODES, 256, 0, stream>>>(X, ew, Ri, Ro, theta, out);
}